// Round 1
// baseline (31.613 us; speedup 1.0000x reference)
//
#include <hip/hip_runtime.h>

// Code_Multiplexing: per batch element b, for each stream i (=position l):
//   c_j = x_j[b,i,0] + I*x_j[b,i,1]
//   out_i[b] = [Re y0, Im y0, Re y1, Im y1, Re y2, Im y2, Re y3, Im y3]
//   y0 = c0+c1+c2+c3
//   y1 = I*(c0-c1+c2-c3)   -> Re=-(ImCombo), Im=ReCombo
//   y2 = c0+c1-c2-c3
//   y3 = I*(c0-c1-c2+c3)
// Memory-bound: 64 MiB in + 64 MiB out.

__global__ __launch_bounds__(256) void Code_Multiplexing_22522808500314_kernel(
    const float* __restrict__ x0, const float* __restrict__ x1,
    const float* __restrict__ x2, const float* __restrict__ x3,
    float* __restrict__ out, int B)
{
    int b = blockIdx.x * blockDim.x + threadIdx.x;
    if (b >= B) return;

    const size_t off = (size_t)b * 8;

    // Load 8 floats per input: [l0.re, l0.im, l1.re, l1.im, l2.re, l2.im, l3.re, l3.im]
    float4 lo[4], hi[4];
    {
        const float4* p;
        p = (const float4*)(x0 + off); lo[0] = p[0]; hi[0] = p[1];
        p = (const float4*)(x1 + off); lo[1] = p[0]; hi[1] = p[1];
        p = (const float4*)(x2 + off); lo[2] = p[0]; hi[2] = p[1];
        p = (const float4*)(x3 + off); lo[3] = p[0]; hi[3] = p[1];
    }

    const size_t stream_stride = (size_t)B * 8;   // floats per output stream block

    #pragma unroll
    for (int i = 0; i < 4; ++i) {
        // a_j = Re(x_j at l=i), b_j = Im(x_j at l=i); compile-time selection
        float a[4], bb[4];
        #pragma unroll
        for (int j = 0; j < 4; ++j) {
            // element index 2*i (re) and 2*i+1 (im) within the 8 floats
            float e0, e1;
            if (i == 0)      { e0 = lo[j].x; e1 = lo[j].y; }
            else if (i == 1) { e0 = lo[j].z; e1 = lo[j].w; }
            else if (i == 2) { e0 = hi[j].x; e1 = hi[j].y; }
            else             { e0 = hi[j].z; e1 = hi[j].w; }
            a[j] = e0; bb[j] = e1;
        }

        const float sa01 = a[0] + a[1],  da01 = a[0] - a[1];
        const float sa23 = a[2] + a[3],  da23 = a[2] - a[3];
        const float sb01 = bb[0] + bb[1], db01 = bb[0] - bb[1];
        const float sb23 = bb[2] + bb[3], db23 = bb[2] - bb[3];

        float4 o0, o1;
        o0.x = sa01 + sa23;            // Re y0
        o0.y = sb01 + sb23;            // Im y0
        o0.z = -(db01 + db23);         // Re y1
        o0.w = da01 + da23;            // Im y1
        o1.x = sa01 - sa23;            // Re y2
        o1.y = sb01 - sb23;            // Im y2
        o1.z = -(db01 - db23);         // Re y3
        o1.w = da01 - da23;            // Im y3

        float4* po = (float4*)(out + (size_t)i * stream_stride + off);
        po[0] = o0;
        po[1] = o1;
    }
}

extern "C" void kernel_launch(void* const* d_in, const int* in_sizes, int n_in,
                              void* d_out, int out_size, void* d_ws, size_t ws_size,
                              hipStream_t stream) {
    const float* x0 = (const float*)d_in[0];
    const float* x1 = (const float*)d_in[1];
    const float* x2 = (const float*)d_in[2];
    const float* x3 = (const float*)d_in[3];
    float* out = (float*)d_out;

    const int B = in_sizes[0] / 8;   // each input is [B, 4, 2] floats
    const int block = 256;
    const int grid = (B + block - 1) / block;
    Code_Multiplexing_22522808500314_kernel<<<grid, block, 0, stream>>>(
        x0, x1, x2, x3, out, B);
}